// Round 5
// baseline (18.001 us; speedup 1.0000x reference)
//
#include <hip/hip_runtime.h>
#include <math.h>

#define HN   512
#define N2M  32
#define LVAL 8192
#define TPB  256
#define STR  136   // f16 per LDS row (128 data + 8 pad); dword stride 68
#define STRD 68

typedef _Float16 f16x8 __attribute__((ext_vector_type(8)));
typedef float    f32x4 __attribute__((ext_vector_type(4)));

// Split x,y into f16 hi + f16 lo residual; store packed dwords (x in low half).
__device__ __forceinline__ void split_store(unsigned* dst_hi, unsigned* dst_lo,
                                            float x, float y) {
    const _Float16 hx = (_Float16)x, hy = (_Float16)y;
    const float lxf = x - (float)hx, lyf = y - (float)hy;
    const _Float16 lx = (_Float16)lxf, ly = (_Float16)lyf;
    const unsigned short ux = __builtin_bit_cast(unsigned short, hx);
    const unsigned short uy = __builtin_bit_cast(unsigned short, hy);
    const unsigned short vx = __builtin_bit_cast(unsigned short, lx);
    const unsigned short vy = __builtin_bit_cast(unsigned short, ly);
    *dst_hi = (unsigned)ux | ((unsigned)uy << 16);
    *dst_lo = (unsigned)vx | ((unsigned)vy << 16);
}

// Per-mode parameter precompute: 1 thread per (h,n). ws[mode*12..] =
// {xl2, ph, pl, c2r, c2i, zr, zi, z64r, z64i, pad...}
__global__ __launch_bounds__(128) void s4d_setup(
    const float* __restrict__ log_dt,
    const float* __restrict__ B_real,
    const float* __restrict__ B_imag,
    const float* __restrict__ Cmat,
    const float* __restrict__ A_real,
    const float* __restrict__ A_imag,
    float* __restrict__ ws)
{
    const int i = blockIdx.x * 128 + threadIdx.x;
    if (i >= HN * N2M) return;
    const int h = i >> 5;
    const float dt  = expf(log_dt[h]);
    const float Are = -expf(A_real[i]) - 1e-6f;
    const float Aim = A_imag[i];
    const float hdt = 0.5f * dt;
    const float dre  = 1.0f - hdt * Are + 1e-6f;
    const float dim_ = -hdt * Aim;
    const float nre = 1.0f + hdt * Are;
    const float nim = hdt * Aim;
    const float inv = 1.0f / (dre * dre + dim_ * dim_);
    const float zr = (nre * dre + nim * dim_) * inv;
    const float zi = (nim * dre - nre * dim_) * inv;
    const float br = B_real[i], bi = B_imag[i];
    const float tbr = dt * ((br * dre + bi * dim_) * inv);
    const float tbi = dt * ((bi * dre - br * dim_) * inv);
    const float Cv = Cmat[i];
    const float c2r = 2.0f * Cv * tbr;
    const float c2i = 2.0f * Cv * tbi;
    const float r2  = zr * zr + zi * zi;
    const float xl2 = 0.5f * log2f(r2);                       // log2|z|
    const float phi = atan2f(zi, zr) * 0.15915494309189535f;  // revolutions
    const float ph  = __uint_as_float(__float_as_uint(phi) & 0xFFFFE000u);
    const float pl  = phi - ph;
    const float e64   = __builtin_amdgcn_exp2f(64.0f * xl2);
    const float rev64 = __builtin_amdgcn_fractf(
        fmaf(64.0f, pl, __builtin_amdgcn_fractf(64.0f * ph)));
    const float z64r = e64 * __builtin_amdgcn_cosf(rev64);
    const float z64i = e64 * __builtin_amdgcn_sinf(rev64);
    float4* w4 = (float4*)(ws + (size_t)i * 12);
    w4[0] = make_float4(xl2, ph, pl, c2r);
    w4[1] = make_float4(c2i, zr, zi, z64r);
    w4[2] = make_float4(z64i, 0.0f, 0.0f, 0.0f);
}

// Block = (l-half bx, head h).
//  A: copy 32 modes x 12 floats of params ws -> LDS (float4 coalesced)
//  B: W table (j-major) + U table (m-major), f16 hi|lo split, via chunk-start
//     transcendentals + complex recurrences
//  C: MFMA 16x16x32_f16: K = Uhi*Whi + Ulo*Whi + Uhi*Wlo
__global__ __launch_bounds__(TPB) void s4d_mfma(
    const float* __restrict__ ws,
    float* __restrict__ out)
{
    __shared__ __align__(16) _Float16 shU[64 * STR];
    __shared__ __align__(16) _Float16 shW[64 * STR];
    __shared__ float4 pm4[N2M * 3];

    const int h  = blockIdx.y;
    const int bx = blockIdx.x;
    const int t  = threadIdx.x;

    // ---- Stage A: param copy ----
    if (t < N2M * 3) {
        pm4[t] = ((const float4*)ws)[h * (N2M * 3) + t];
    }
    __syncthreads();
    const float* pm = (const float*)pm4;

    // ---- Stage B1: W table. thread -> (mode n = t>>3, j0 = (t&7)*8) ----
    {
        const int n  = t >> 3;
        const int j0 = (t & 7) * 8;
        const float xl2 = pm[n * 12 + 0], ph = pm[n * 12 + 1], pl = pm[n * 12 + 2];
        const float zr  = pm[n * 12 + 5], zi = pm[n * 12 + 6];
        const float j0f = (float)j0;
        const float e   = __builtin_amdgcn_exp2f(j0f * xl2);
        const float rev = __builtin_amdgcn_fractf(
            fmaf(j0f, pl, __builtin_amdgcn_fractf(j0f * ph)));
        float wr = e * __builtin_amdgcn_cosf(rev);
        float wi = e * __builtin_amdgcn_sinf(rev);
        unsigned* dw = (unsigned*)shW;
#pragma unroll
        for (int jj = 0; jj < 8; ++jj) {
            const int j = j0 + jj;
            split_store(dw + j * STRD + n, dw + j * STRD + 32 + n, wr, -wi);
            const float nwr = wr * zr - wi * zi;
            wi = fmaf(wr, zi, wi * zr);
            wr = nwr;
        }
    }

    // ---- Stage B2: U table. thread -> (mode n = t>>3, m0 = (t&7)*8) ----
    {
        const int n  = t >> 3;
        const int m0 = (t & 7) * 8;
        const float xl2 = pm[n * 12 + 0], ph = pm[n * 12 + 1], pl = pm[n * 12 + 2];
        const float c2r = pm[n * 12 + 3], c2i = pm[n * 12 + 4];
        const float z64r = pm[n * 12 + 7], z64i = pm[n * 12 + 8];
        const float l0f = (float)((bx << 12) + (m0 << 6));  // 64*(64*bx+m0): exact
        const float e   = __builtin_amdgcn_exp2f(l0f * xl2);
        const float rev = __builtin_amdgcn_fractf(
            fmaf(l0f, pl, __builtin_amdgcn_fractf(l0f * ph)));
        const float cs_ = __builtin_amdgcn_cosf(rev);
        const float sn_ = __builtin_amdgcn_sinf(rev);
        float ur = e * fmaf(c2r, cs_, -(c2i * sn_));
        float ui = e * fmaf(c2r, sn_, c2i * cs_);
        unsigned* dw = (unsigned*)shU;
#pragma unroll
        for (int mm = 0; mm < 8; ++mm) {
            const int m = m0 + mm;
            split_store(dw + m * STRD + n, dw + m * STRD + 32 + n, ur, ui);
            const float nur = ur * z64r - ui * z64i;
            ui = fmaf(ur, z64i, ui * z64r);
            ur = nur;
        }
    }
    __syncthreads();

    // ---- Stage C: MFMA. wave w owns rows [16w,16w+16); jt = 0..3 ----
    const int w = t >> 6, lane = t & 63, g = lane >> 4, r = lane & 15;
    const _Float16* ua = shU + (w * 16 + r) * STR + g * 8;
    const f16x8 A0 = *(const f16x8*)(ua);        // U_hi k 0-31
    const f16x8 A1 = *(const f16x8*)(ua + 32);   // U_hi k 32-63
    const f16x8 A2 = *(const f16x8*)(ua + 64);   // U_lo k 0-31
    const f16x8 A3 = *(const f16x8*)(ua + 96);   // U_lo k 32-63
    float* outp = out + (size_t)h * LVAL + (bx << 12);
#pragma unroll
    for (int jt = 0; jt < 4; ++jt) {
        const _Float16* wb = shW + (jt * 16 + r) * STR + g * 8;
        const f16x8 B0 = *(const f16x8*)(wb);        // W_hi k 0-31
        const f16x8 B1 = *(const f16x8*)(wb + 32);   // W_hi k 32-63
        const f16x8 B2 = *(const f16x8*)(wb + 64);   // W_lo k 0-31
        const f16x8 B3 = *(const f16x8*)(wb + 96);   // W_lo k 32-63
        f32x4 acc = {0.f, 0.f, 0.f, 0.f};
        acc = __builtin_amdgcn_mfma_f32_16x16x32_f16(A0, B0, acc, 0, 0, 0);
        acc = __builtin_amdgcn_mfma_f32_16x16x32_f16(A1, B1, acc, 0, 0, 0);
        acc = __builtin_amdgcn_mfma_f32_16x16x32_f16(A2, B0, acc, 0, 0, 0);
        acc = __builtin_amdgcn_mfma_f32_16x16x32_f16(A3, B1, acc, 0, 0, 0);
        acc = __builtin_amdgcn_mfma_f32_16x16x32_f16(A0, B2, acc, 0, 0, 0);
        acc = __builtin_amdgcn_mfma_f32_16x16x32_f16(A1, B3, acc, 0, 0, 0);
        const int jcol = jt * 16 + r;
#pragma unroll
        for (int rr = 0; rr < 4; ++rr) {
            const int m_local = w * 16 + g * 4 + rr;   // C/D: row=(lane>>4)*4+reg
            outp[m_local * 64 + jcol] = acc[rr];
        }
    }
}

extern "C" void kernel_launch(void* const* d_in, const int* in_sizes, int n_in,
                              void* d_out, int out_size, void* d_ws, size_t ws_size,
                              hipStream_t stream)
{
    const float* log_dt = (const float*)d_in[0];
    const float* B_real = (const float*)d_in[1];
    const float* B_imag = (const float*)d_in[2];
    const float* Cmat   = (const float*)d_in[3];
    // d_in[4] = Kc (unused by reference)
    const float* A_real = (const float*)d_in[5];
    const float* A_imag = (const float*)d_in[6];
    // d_in[7] = L (fixed 8192)
    float* out = (float*)d_out;
    float* ws  = (float*)d_ws;   // 16384 modes * 12 floats = 768 KB

    s4d_setup<<<dim3((HN * N2M) / 128), dim3(128), 0, stream>>>(
        log_dt, B_real, B_imag, Cmat, A_real, A_imag, ws);

    dim3 grid(2, HN);   // (l-half, head) = 1024 blocks
    s4d_mfma<<<grid, dim3(TPB), 0, stream>>>(ws, out);
}

// Round 7
// 11.996 us; speedup vs baseline: 1.5006x; 1.5006x over previous
//
#include <hip/hip_runtime.h>
#include <math.h>

#define HN   512
#define N2M  32
#define LVAL 8192
#define TPB  512
#define STR  136   // f16 per LDS row (128 data + 8 pad)
#define STRD 68    // dword row stride

typedef _Float16 f16x8 __attribute__((ext_vector_type(8)));
typedef __fp16   pk16x2 __attribute__((ext_vector_type(2)));
typedef float    f32x4 __attribute__((ext_vector_type(4)));

// Split (x,y) into packed f16 hi + f16 lo residual via v_cvt_pkrtz (1 instr per pack).
__device__ __forceinline__ void split_store_pk(unsigned* dhi, unsigned* dlo,
                                               float x, float y) {
    const pk16x2 hi = __builtin_amdgcn_cvt_pkrtz(x, y);
    const float rx = x - (float)hi.x;
    const float ry = y - (float)hi.y;
    const pk16x2 lo = __builtin_amdgcn_cvt_pkrtz(rx, ry);
    *dhi = __builtin_bit_cast(unsigned, hi);
    *dlo = __builtin_bit_cast(unsigned, lo);
}

// One block per head h. l = 64*m + j, m in 0..127 (U table), j in 0..63 (W table).
//  Stage 1 (t<32): per-mode params -> pm LDS
//  Stage B: W[j] = z^j (stored (wr,-wi)), U[m] = c2*z^(64m) (stored (ur,ui)),
//           f16 hi|lo split, thread strides rows by 16 (steps z^16 / z^1024) ->
//           LDS write banks (4*lg+n)%32 = exact 2-way (free).
//  Stage C: MFMA 16x16x32_f16, A=W-tile (D rows = j), B=U-tile (D cols = m):
//           K = Whi*Uhi + Wlo*Uhi + Whi*Ulo; lane's 4 acc regs = 4 consecutive l
//           -> one float4 store per jt.
__global__ __launch_bounds__(TPB, 4) void s4d_mfma(
    const float* __restrict__ log_dt,
    const float* __restrict__ B_real,
    const float* __restrict__ B_imag,
    const float* __restrict__ Cmat,
    const float* __restrict__ A_real,
    const float* __restrict__ A_imag,
    float* __restrict__ out)
{
    __shared__ __align__(16) _Float16 shU[128 * STR];
    __shared__ __align__(16) _Float16 shW[64 * STR];
    __shared__ float pm[N2M][12];

    const int h = blockIdx.x;
    const int t = threadIdx.x;

    // ---- Stage 1: per-mode params ----
    if (t < N2M) {
        const int idx = h * N2M + t;
        const float dt  = expf(log_dt[h]);
        const float Are = -expf(A_real[idx]) - 1e-6f;
        const float Aim = A_imag[idx];
        const float hdt = 0.5f * dt;
        const float dre  = 1.0f - hdt * Are + 1e-6f;
        const float dim_ = -hdt * Aim;
        const float nre = 1.0f + hdt * Are;
        const float nim = hdt * Aim;
        const float inv = 1.0f / (dre * dre + dim_ * dim_);
        const float zr = (nre * dre + nim * dim_) * inv;
        const float zi = (nim * dre - nre * dim_) * inv;
        const float br = B_real[idx], bi = B_imag[idx];
        const float tbr = dt * ((br * dre + bi * dim_) * inv);
        const float tbi = dt * ((bi * dre - br * dim_) * inv);
        const float Cv = Cmat[idx];
        const float c2r = 2.0f * Cv * tbr;
        const float c2i = 2.0f * Cv * tbi;
        const float r2  = zr * zr + zi * zi;
        const float xl2 = 0.5f * log2f(r2);                       // log2|z|
        const float phi = atan2f(zi, zr) * 0.15915494309189535f;  // revolutions
        const float ph  = __uint_as_float(__float_as_uint(phi) & 0xFFFFE000u);
        const float pl  = phi - ph;
        // z^16 (W row step)
        const float e16   = __builtin_amdgcn_exp2f(16.0f * xl2);
        const float rv16  = __builtin_amdgcn_fractf(
            fmaf(16.0f, pl, __builtin_amdgcn_fractf(16.0f * ph)));
        const float z16r = e16 * __builtin_amdgcn_cosf(rv16);
        const float z16i = e16 * __builtin_amdgcn_sinf(rv16);
        // z^1024 (U row step: 64*16)
        const float e1k   = __builtin_amdgcn_exp2f(1024.0f * xl2);
        const float rv1k  = __builtin_amdgcn_fractf(
            fmaf(1024.0f, pl, __builtin_amdgcn_fractf(1024.0f * ph)));
        const float zkr = e1k * __builtin_amdgcn_cosf(rv1k);
        const float zki = e1k * __builtin_amdgcn_sinf(rv1k);
        pm[t][0] = xl2; pm[t][1] = ph;  pm[t][2] = pl;
        pm[t][3] = c2r; pm[t][4] = c2i;
        pm[t][5] = z16r; pm[t][6] = z16i;
        pm[t][7] = zkr;  pm[t][8] = zki;
    }
    __syncthreads();

    const int n  = t >> 4;    // mode 0..31
    const int lg = t & 15;    // row group 0..15
    const float xl2 = pm[n][0], ph = pm[n][1], pl = pm[n][2];

    // ---- Stage B1: W table, rows j = lg + 16s ----
    {
        const float jf  = (float)lg;
        const float e   = __builtin_amdgcn_exp2f(jf * xl2);
        const float rev = __builtin_amdgcn_fractf(
            fmaf(jf, pl, __builtin_amdgcn_fractf(jf * ph)));
        float wr = e * __builtin_amdgcn_cosf(rev);
        float wi = e * __builtin_amdgcn_sinf(rev);
        const float sr = pm[n][5], si = pm[n][6];
        unsigned* dw = (unsigned*)shW;
#pragma unroll
        for (int s = 0; s < 4; ++s) {
            const int j = lg + 16 * s;
            split_store_pk(dw + j * STRD + n, dw + j * STRD + 32 + n, wr, -wi);
            const float nr = wr * sr - wi * si;
            wi = fmaf(wr, si, wi * sr);
            wr = nr;
        }
    }

    // ---- Stage B2: U table, rows m = lg + 16s ----
    {
        const float l0f = (float)(lg << 6);   // 64*lg, exact
        const float e   = __builtin_amdgcn_exp2f(l0f * xl2);
        const float rev = __builtin_amdgcn_fractf(
            fmaf(l0f, pl, __builtin_amdgcn_fractf(l0f * ph)));
        const float cs_ = __builtin_amdgcn_cosf(rev);
        const float sn_ = __builtin_amdgcn_sinf(rev);
        const float c2r = pm[n][3], c2i = pm[n][4];
        float ur = e * fmaf(c2r, cs_, -(c2i * sn_));
        float ui = e * fmaf(c2r, sn_, c2i * cs_);
        const float sr = pm[n][7], si = pm[n][8];
        unsigned* du = (unsigned*)shU;
#pragma unroll
        for (int s = 0; s < 8; ++s) {
            const int m = lg + 16 * s;
            split_store_pk(du + m * STRD + n, du + m * STRD + 32 + n, ur, ui);
            const float nr = ur * sr - ui * si;
            ui = fmaf(ur, si, ui * sr);
            ur = nr;
        }
    }
    __syncthreads();

    // ---- Stage C: 8 waves, wave w owns m-tile [16w, 16w+16) as B-operand ----
    const int w = t >> 6, lane = t & 63, g = lane >> 4, r = lane & 15;
    const _Float16* ub = shU + (w * 16 + r) * STR + g * 8;
    const f16x8 B0 = *(const f16x8*)(ub);        // U_hi k 0-31
    const f16x8 B1 = *(const f16x8*)(ub + 32);   // U_hi k 32-63
    const f16x8 B2 = *(const f16x8*)(ub + 64);   // U_lo k 0-31
    const f16x8 B3 = *(const f16x8*)(ub + 96);   // U_lo k 32-63
    float* outp = out + (size_t)h * LVAL;
#pragma unroll
    for (int jt = 0; jt < 4; ++jt) {
        const _Float16* wa = shW + (jt * 16 + r) * STR + g * 8;
        const f16x8 A0 = *(const f16x8*)(wa);        // W_hi k 0-31
        const f16x8 A1 = *(const f16x8*)(wa + 32);   // W_hi k 32-63
        const f16x8 A2 = *(const f16x8*)(wa + 64);   // W_lo k 0-31
        const f16x8 A3 = *(const f16x8*)(wa + 96);   // W_lo k 32-63
        f32x4 acc = {0.f, 0.f, 0.f, 0.f};
        acc = __builtin_amdgcn_mfma_f32_16x16x32_f16(A0, B0, acc, 0, 0, 0);
        acc = __builtin_amdgcn_mfma_f32_16x16x32_f16(A1, B1, acc, 0, 0, 0);
        acc = __builtin_amdgcn_mfma_f32_16x16x32_f16(A2, B0, acc, 0, 0, 0);
        acc = __builtin_amdgcn_mfma_f32_16x16x32_f16(A3, B1, acc, 0, 0, 0);
        acc = __builtin_amdgcn_mfma_f32_16x16x32_f16(A0, B2, acc, 0, 0, 0);
        acc = __builtin_amdgcn_mfma_f32_16x16x32_f16(A1, B3, acc, 0, 0, 0);
        // D: col = m_local = r (+16w), row = j_local = 4g + rr (+16jt)
        // l = 64*(16w + r) + 16*jt + 4g + rr  -> 4 consecutive l per lane
        float4 v = make_float4(acc[0], acc[1], acc[2], acc[3]);
        *(float4*)(outp + 64 * (16 * w + r) + 16 * jt + 4 * g) = v;
    }
}

extern "C" void kernel_launch(void* const* d_in, const int* in_sizes, int n_in,
                              void* d_out, int out_size, void* d_ws, size_t ws_size,
                              hipStream_t stream)
{
    const float* log_dt = (const float*)d_in[0];
    const float* B_real = (const float*)d_in[1];
    const float* B_imag = (const float*)d_in[2];
    const float* Cmat   = (const float*)d_in[3];
    // d_in[4] = Kc (unused by reference)
    const float* A_real = (const float*)d_in[5];
    const float* A_imag = (const float*)d_in[6];
    // d_in[7] = L (fixed 8192)
    float* out = (float*)d_out;

    s4d_mfma<<<dim3(HN), dim3(TPB), 0, stream>>>(log_dt, B_real, B_imag, Cmat,
                                                 A_real, A_imag, out);
}